// Round 9
// baseline (244.922 us; speedup 1.0000x reference)
//
#include <hip/hip_runtime.h>
#include <math.h>

#define SEQ   2048
#define DH    64
#define NBH   24
// scale * log2(e): softmax in exp2 domain
#define QSCALE 0.18033688011112042f

typedef __attribute__((ext_vector_type(8))) short short8;
typedef __attribute__((ext_vector_type(4))) float f32x4;
typedef __attribute__((ext_vector_type(4))) int   int4v;

#define MFMA(a, b, c) __builtin_amdgcn_mfma_f32_16x16x32_bf16((a), (b), (c), 0, 0, 0)

__device__ __forceinline__ unsigned bf16u(float f) {   // RNE-rounded, result in high 16
    union { float f; unsigned u; } x; x.f = f;
    return x.u + 0x7fffu + ((x.u >> 16) & 1u);
}
__device__ __forceinline__ unsigned pack_bf162(float lo, float hi) {
    return (bf16u(lo) >> 16) | (bf16u(hi) & 0xffff0000u);
}

// ---- pre-pass: grid.z=0 -> Q(+scale),K fp32->bf16; grid.z=1 -> V -> V^T ----
__global__ __launch_bounds__(256)
void cvt_all(const float* __restrict__ q, const float* __restrict__ k,
             const float* __restrict__ v,
             short* __restrict__ qb, short* __restrict__ kb,
             short* __restrict__ vt)
{
    const int t  = threadIdx.x;
    const int bh = blockIdx.x;
    const int s0 = blockIdx.y * 64;
    const size_t base = ((size_t)bh * SEQ + s0) * DH;

    if (blockIdx.z == 0) {
        #pragma unroll
        for (int i = 0; i < 4; ++i) {
            const int idx = i * 256 + t;
            float4 a = ((const float4*)(q + base))[idx];
            ((int2*)(qb + base))[idx] = make_int2(
                (int)pack_bf162(a.x * QSCALE, a.y * QSCALE),
                (int)pack_bf162(a.z * QSCALE, a.w * QSCALE));
            float4 b = ((const float4*)(k + base))[idx];
            ((int2*)(kb + base))[idx] = make_int2(
                (int)pack_bf162(b.x, b.y), (int)pack_bf162(b.z, b.w));
        }
        return;
    }

    __shared__ float tile[64][65];
    {
        const int sl = t >> 2, cg = (t & 3) * 16;
        const float* src = v + base + (size_t)sl * DH + cg;
        #pragma unroll
        for (int i = 0; i < 4; ++i)
            *(float4*)(&tile[sl][cg + 4 * i]) = ((const float4*)src)[i];
    }
    __syncthreads();
    {
        const int dl = t >> 2, sg = (t & 3) * 16;
        float f[16];
        #pragma unroll
        for (int j = 0; j < 16; ++j) f[j] = tile[sg + j][dl];
        short8 r0, r1;
        #pragma unroll
        for (int j = 0; j < 4; ++j) {
            ((int*)&r0)[j] = (int)pack_bf162(f[2 * j],     f[2 * j + 1]);
            ((int*)&r1)[j] = (int)pack_bf162(f[8 + 2 * j], f[9 + 2 * j]);
        }
        short* dst = vt + (size_t)bh * DH * SEQ + (size_t)dl * SEQ + s0 + sg;
        *(short8*)(dst)     = r0;
        *(short8*)(dst + 8) = r1;
    }
}

// ---- main: pipelined split-K flash, 32 q-rows/wave, 64-col chunks ----
// R6 structure (2-way khalf split, 16 iters/wave) with a software-pipelined
// iter loop. Key resource trick: after softmax extracts packed W, c[] is
// DEAD -> next iter's S-MFMAs recycle the same c registers (R5's pipeline
// needed a second accumulator set and spilled; this one doesn't).
// Per iter: [av0 loads][ka(next) loads] -> softmax (covers av0/ka latency)
// -> PV(kch0) + S(next,mt0,1) -> av1 loads -> PV(kch1) + S(next,mt2,3).
// launch_bounds(256,3): ~170-reg cap. (256,4)=128 spilled 3x (R3/R5/R7);
// never tighten without checking WRITE_SIZE (spill -> hundreds of MB).
__global__ __launch_bounds__(256, 3)
void attn_fwd(const short* __restrict__ qb, const short* __restrict__ kb,
              const short* __restrict__ vt, float* __restrict__ og)
{
    __shared__ float lds_o[2][2][64][16];
    __shared__ float lds_m[2][2][16];
    __shared__ float lds_l[2][2][16];

    const int lane  = threadIdx.x & 63;
    const int wave  = threadIdx.x >> 6;
    const int qgrp  = wave >> 1;
    const int khalf = wave & 1;
    const int quad  = lane >> 4;
    const int l16   = lane & 15;
    const int bh    = blockIdx.x;
    const int q0    = blockIdx.y * 64 + qgrp * 32;

    const short* kbase = kb + (size_t)bh * SEQ * DH;
    const short* vbase = vt + (size_t)bh * DH * SEQ;

    short8 bq[2][2];
    #pragma unroll
    for (int qs = 0; qs < 2; ++qs) {
        const short* qrow = qb + ((size_t)(bh * SEQ + q0 + qs * 16 + l16)) * DH + quad * 8;
        bq[qs][0] = *(const short8*)(qrow);
        bq[qs][1] = *(const short8*)(qrow + 32);
    }

    f32x4 o[2][4];
    float m_i[2], l_i[2];
    #pragma unroll
    for (int qs = 0; qs < 2; ++qs) {
        m_i[qs] = -INFINITY; l_i[qs] = 0.f;
        #pragma unroll
        for (int dt = 0; dt < 4; ++dt) o[qs][dt] = (f32x4){0.f, 0.f, 0.f, 0.f};
    }

    const unsigned psel  = (quad < 2) ? 0x05040100u : 0x07060302u;
    const int      srcLo = l16 + ((quad & 1) << 5);
    const int      srcHi = srcLo + 16;

    const size_t klane = (size_t)l16 * DH + quad * 8;
    const size_t vlane = (size_t)l16 * SEQ + quad * 8;

    // ---- prologue: K frags + S of first chunk
    short8 ka[8];
    int k0 = khalf * (SEQ / 2);
    #pragma unroll
    for (int mt = 0; mt < 4; ++mt) {
        const short* krow = kbase + (size_t)(k0 + mt * 16) * DH + klane;
        ka[2 * mt]     = *(const short8*)(krow);
        ka[2 * mt + 1] = *(const short8*)(krow + 32);
    }
    f32x4 c[2][4];
    #pragma unroll
    for (int mt = 0; mt < 4; ++mt)
        #pragma unroll
        for (int qs = 0; qs < 2; ++qs) {
            f32x4 z = (f32x4){0.f, 0.f, 0.f, 0.f};
            z = MFMA(ka[2 * mt],     bq[qs][0], z);
            z = MFMA(ka[2 * mt + 1], bq[qs][1], z);
            c[qs][mt] = z;
        }

    #pragma unroll 1
    for (int iter = 0; iter < 16; ++iter, k0 += 64) {
        const bool more = (iter < 15);

        // ---- V frags for kch0: issued first, land during softmax
        short8 av0[4];
        #pragma unroll
        for (int dt = 0; dt < 4; ++dt)
            av0[dt] = *(const short8*)(vbase + (size_t)(dt * 16) * SEQ + vlane + k0);

        // ---- K frags for next iter (consumed by interleaved S-MFMAs below)
        if (more) {
            #pragma unroll
            for (int mt = 0; mt < 4; ++mt) {
                const short* krow = kbase + (size_t)(k0 + 64 + mt * 16) * DH + klane;
                ka[2 * mt]     = *(const short8*)(krow);
                ka[2 * mt + 1] = *(const short8*)(krow + 32);
            }
        }

        // ---- online softmax; c dies into packed W
        int W[2][8];
        #pragma unroll
        for (int qs = 0; qs < 2; ++qs) {
            float tm[4];
            #pragma unroll
            for (int e = 0; e < 4; ++e)
                tm[e] = fmaxf(fmaxf(c[qs][0][e], c[qs][1][e]),
                              fmaxf(c[qs][2][e], c[qs][3][e]));
            float vmax = fmaxf(fmaxf(tm[0], tm[1]), fmaxf(tm[2], tm[3]));
            vmax = fmaxf(vmax, m_i[qs]);
            vmax = fmaxf(vmax, __shfl_xor(vmax, 16, 64));
            vmax = fmaxf(vmax, __shfl_xor(vmax, 32, 64));
            const float alpha = __builtin_amdgcn_exp2f(m_i[qs] - vmax);
            m_i[qs] = vmax;

            float rs0 = 0.f, rs1 = 0.f;
            #pragma unroll
            for (int i2 = 0; i2 < 2; ++i2)
                #pragma unroll
                for (int r = 0; r < 4; ++r) {
                    float p0 = __builtin_amdgcn_exp2f(c[qs][2 * i2][r]     - vmax);
                    float p1 = __builtin_amdgcn_exp2f(c[qs][2 * i2 + 1][r] - vmax);
                    rs0 += p0; rs1 += p1;
                    W[qs][i2 * 4 + r] = (int)pack_bf162(p0, p1);
                }
            float rs = rs0 + rs1;
            rs += __shfl_xor(rs, 16, 64);
            rs += __shfl_xor(rs, 32, 64);
            l_i[qs] = l_i[qs] * alpha + rs;
            #pragma unroll
            for (int dt = 0; dt < 4; ++dt)
                #pragma unroll
                for (int r = 0; r < 4; ++r) o[qs][dt][r] *= alpha;
        }

        // ---- group 0: transform+PV kch0 (av0), then S(next) mt 0,1 into c
        #pragma unroll
        for (int qs = 0; qs < 2; ++qs) {
            int sA[4], sB[4];
            #pragma unroll
            for (int r = 0; r < 4; ++r) {
                int w = W[qs][r];
                sA[r] = __shfl(w, srcLo, 64);
                sB[r] = __shfl(w, srcHi, 64);
            }
            int4v pw;
            pw[0] = (int)__builtin_amdgcn_perm((unsigned)sA[1], (unsigned)sA[0], psel);
            pw[1] = (int)__builtin_amdgcn_perm((unsigned)sA[3], (unsigned)sA[2], psel);
            pw[2] = (int)__builtin_amdgcn_perm((unsigned)sB[1], (unsigned)sB[0], psel);
            pw[3] = (int)__builtin_amdgcn_perm((unsigned)sB[3], (unsigned)sB[2], psel);
            short8 pf = __builtin_bit_cast(short8, pw);
            #pragma unroll
            for (int dt = 0; dt < 4; ++dt)
                o[qs][dt] = MFMA(av0[dt], pf, o[qs][dt]);
        }

        // V frags for kch1 (land during group-1 transform / S-MFMAs)
        short8 av1[4];
        #pragma unroll
        for (int dt = 0; dt < 4; ++dt)
            av1[dt] = *(const short8*)(vbase + (size_t)(dt * 16) * SEQ + vlane + k0 + 32);

        if (more) {
            #pragma unroll
            for (int mt = 0; mt < 2; ++mt)
                #pragma unroll
                for (int qs = 0; qs < 2; ++qs) {
                    f32x4 z = (f32x4){0.f, 0.f, 0.f, 0.f};
                    z = MFMA(ka[2 * mt],     bq[qs][0], z);
                    z = MFMA(ka[2 * mt + 1], bq[qs][1], z);
                    c[qs][mt] = z;
                }
        }

        // ---- group 1: transform+PV kch1 (av1), then S(next) mt 2,3 into c
        #pragma unroll
        for (int qs = 0; qs < 2; ++qs) {
            int sA[4], sB[4];
            #pragma unroll
            for (int r = 0; r < 4; ++r) {
                int w = W[qs][4 + r];
                sA[r] = __shfl(w, srcLo, 64);
                sB[r] = __shfl(w, srcHi, 64);
            }
            int4v pw;
            pw[0] = (int)__builtin_amdgcn_perm((unsigned)sA[1], (unsigned)sA[0], psel);
            pw[1] = (int)__builtin_amdgcn_perm((unsigned)sA[3], (unsigned)sA[2], psel);
            pw[2] = (int)__builtin_amdgcn_perm((unsigned)sB[1], (unsigned)sB[0], psel);
            pw[3] = (int)__builtin_amdgcn_perm((unsigned)sB[3], (unsigned)sB[2], psel);
            short8 pf = __builtin_bit_cast(short8, pw);
            #pragma unroll
            for (int dt = 0; dt < 4; ++dt)
                o[qs][dt] = MFMA(av1[dt], pf, o[qs][dt]);
        }

        if (more) {
            #pragma unroll
            for (int mt = 2; mt < 4; ++mt)
                #pragma unroll
                for (int qs = 0; qs < 2; ++qs) {
                    f32x4 z = (f32x4){0.f, 0.f, 0.f, 0.f};
                    z = MFMA(ka[2 * mt],     bq[qs][0], z);
                    z = MFMA(ka[2 * mt + 1], bq[qs][1], z);
                    c[qs][mt] = z;
                }
        }
    }

    // ---- cross-wave flash merge (khalf 1 -> LDS, khalf 0 combines+stores)
    if (khalf == 1) {
        #pragma unroll
        for (int qs = 0; qs < 2; ++qs) {
            #pragma unroll
            for (int dt = 0; dt < 4; ++dt)
                #pragma unroll
                for (int r = 0; r < 4; ++r)
                    lds_o[qgrp][qs][lane][dt * 4 + r] = o[qs][dt][r];
            if (quad == 0) {
                lds_m[qgrp][qs][l16] = m_i[qs];
                lds_l[qgrp][qs][l16] = l_i[qs];
            }
        }
    }
    __syncthreads();
    if (khalf == 0) {
        #pragma unroll
        for (int qs = 0; qs < 2; ++qs) {
            const float m2 = lds_m[qgrp][qs][l16];
            const float l2 = lds_l[qgrp][qs][l16];
            const float m  = fmaxf(m_i[qs], m2);
            const float a1 = __builtin_amdgcn_exp2f(m_i[qs] - m);
            const float a2 = __builtin_amdgcn_exp2f(m2 - m);
            const float linv = 1.0f / (l_i[qs] * a1 + l2 * a2);
            float* orow = og + ((size_t)(bh * SEQ + q0 + qs * 16 + l16)) * DH;
            #pragma unroll
            for (int dt = 0; dt < 4; ++dt) {
                f32x4 st;
                #pragma unroll
                for (int r = 0; r < 4; ++r)
                    st[r] = (o[qs][dt][r] * a1
                           + lds_o[qgrp][qs][lane][dt * 4 + r] * a2) * linv;
                *(f32x4*)(orow + dt * 16 + quad * 4) = st;
            }
        }
    }
}

extern "C" void kernel_launch(void* const* d_in, const int* in_sizes, int n_in,
                              void* d_out, int out_size, void* d_ws, size_t ws_size,
                              hipStream_t stream)
{
    const float* q = (const float*)d_in[0];
    const float* k = (const float*)d_in[1];
    const float* v = (const float*)d_in[2];
    float* o = (float*)d_out;

    const size_t nelem = (size_t)NBH * SEQ * DH;
    short* qb  = (short*)d_ws;
    short* kbp = qb + nelem;
    short* vtp = kbp + nelem;   // 18.9 MB total

    cvt_all<<<dim3(NBH, SEQ / 64, 2), 256, 0, stream>>>(q, k, v, qb, kbp, vtp);
    attn_fwd<<<dim3(NBH, SEQ / 64), 256, 0, stream>>>(qb, kbp, vtp, o);
}

// Round 10
// 196.337 us; speedup vs baseline: 1.2475x; 1.2475x over previous
//
#include <hip/hip_runtime.h>
#include <math.h>

#define SEQ   2048
#define DH    64
#define NBH   24
// scale * log2(e): softmax in exp2 domain
#define QSCALE 0.18033688011112042f

typedef __attribute__((ext_vector_type(8))) short short8;
typedef __attribute__((ext_vector_type(4))) float f32x4;
typedef __attribute__((ext_vector_type(4))) int   int4v;

#define MFMA(a, b, c) __builtin_amdgcn_mfma_f32_16x16x32_bf16((a), (b), (c), 0, 0, 0)

__device__ __forceinline__ unsigned bf16u(float f) {   // RNE-rounded, result in high 16
    union { float f; unsigned u; } x; x.f = f;
    return x.u + 0x7fffu + ((x.u >> 16) & 1u);
}
__device__ __forceinline__ unsigned pack_bf162(float lo, float hi) {
    return (bf16u(lo) >> 16) | (bf16u(hi) & 0xffff0000u);
}

// ---- pre-pass: grid.z=0 -> Q(+scale),K fp32->bf16; grid.z=1 -> V -> V^T ----
__global__ __launch_bounds__(256)
void cvt_all(const float* __restrict__ q, const float* __restrict__ k,
             const float* __restrict__ v,
             short* __restrict__ qb, short* __restrict__ kb,
             short* __restrict__ vt)
{
    const int t  = threadIdx.x;
    const int bh = blockIdx.x;
    const int s0 = blockIdx.y * 64;
    const size_t base = ((size_t)bh * SEQ + s0) * DH;

    if (blockIdx.z == 0) {
        #pragma unroll
        for (int i = 0; i < 4; ++i) {
            const int idx = i * 256 + t;
            float4 a = ((const float4*)(q + base))[idx];
            ((int2*)(qb + base))[idx] = make_int2(
                (int)pack_bf162(a.x * QSCALE, a.y * QSCALE),
                (int)pack_bf162(a.z * QSCALE, a.w * QSCALE));
            float4 b = ((const float4*)(k + base))[idx];
            ((int2*)(kb + base))[idx] = make_int2(
                (int)pack_bf162(b.x, b.y), (int)pack_bf162(b.z, b.w));
        }
        return;
    }

    __shared__ float tile[64][65];
    {
        const int sl = t >> 2, cg = (t & 3) * 16;
        const float* src = v + base + (size_t)sl * DH + cg;
        #pragma unroll
        for (int i = 0; i < 4; ++i)
            *(float4*)(&tile[sl][cg + 4 * i]) = ((const float4*)src)[i];
    }
    __syncthreads();
    {
        const int dl = t >> 2, sg = (t & 3) * 16;
        float f[16];
        #pragma unroll
        for (int j = 0; j < 16; ++j) f[j] = tile[sg + j][dl];
        short8 r0, r1;
        #pragma unroll
        for (int j = 0; j < 4; ++j) {
            ((int*)&r0)[j] = (int)pack_bf162(f[2 * j],     f[2 * j + 1]);
            ((int*)&r1)[j] = (int)pack_bf162(f[8 + 2 * j], f[9 + 2 * j]);
        }
        short* dst = vt + (size_t)bh * DH * SEQ + (size_t)dl * SEQ + s0 + sg;
        *(short8*)(dst)     = r0;
        *(short8*)(dst + 8) = r1;
    }
}

// ---- main: R6 split-K flash with load-hoisted iter (issue-order only) ----
// EXACT R6 dataflow (99.7us proven) -- the only change is VMEM issue order:
//   S-MFMA(ka, cur) -> issue 8 av loads -> softmax (~450cyc, covers av)
//   -> issue next ka loads (c dead, W replaces: net-zero live)
//   -> transform+PV (~400cyc, covers ka latency for next iter's S).
// No second score set, no MFMA motion (R9's interleave spilled: 173us,
// WRITE 411MB). Peak live ~145 regs < (256,3)'s ~170 cap.
// Spill history: (256,4)=128 cap spilled R3/R5/R7; R9's structure spilled
// even at (256,3). Tripwire: WRITE_SIZE must stay ~12 MB.
__global__ __launch_bounds__(256, 3)
void attn_fwd(const short* __restrict__ qb, const short* __restrict__ kb,
              const short* __restrict__ vt, float* __restrict__ og)
{
    __shared__ float lds_o[2][2][64][16];
    __shared__ float lds_m[2][2][16];
    __shared__ float lds_l[2][2][16];

    const int lane  = threadIdx.x & 63;
    const int wave  = threadIdx.x >> 6;
    const int qgrp  = wave >> 1;
    const int khalf = wave & 1;
    const int quad  = lane >> 4;
    const int l16   = lane & 15;
    const int bh    = blockIdx.x;
    const int q0    = blockIdx.y * 64 + qgrp * 32;

    const short* kbase = kb + (size_t)bh * SEQ * DH;
    const short* vbase = vt + (size_t)bh * DH * SEQ;

    short8 bq[2][2];
    #pragma unroll
    for (int qs = 0; qs < 2; ++qs) {
        const short* qrow = qb + ((size_t)(bh * SEQ + q0 + qs * 16 + l16)) * DH + quad * 8;
        bq[qs][0] = *(const short8*)(qrow);
        bq[qs][1] = *(const short8*)(qrow + 32);
    }

    f32x4 o[2][4];
    float m_i[2], l_i[2];
    #pragma unroll
    for (int qs = 0; qs < 2; ++qs) {
        m_i[qs] = -INFINITY; l_i[qs] = 0.f;
        #pragma unroll
        for (int dt = 0; dt < 4; ++dt) o[qs][dt] = (f32x4){0.f, 0.f, 0.f, 0.f};
    }

    const unsigned psel  = (quad < 2) ? 0x05040100u : 0x07060302u;
    const int      srcLo = l16 + ((quad & 1) << 5);
    const int      srcHi = srcLo + 16;

    const size_t klane = (size_t)l16 * DH + quad * 8;
    const size_t vlane = (size_t)l16 * SEQ + quad * 8;

    // prologue: K frags of first chunk
    short8 ka[8];
    int k0 = khalf * (SEQ / 2);
    #pragma unroll
    for (int mt = 0; mt < 4; ++mt) {
        const short* krow = kbase + (size_t)(k0 + mt * 16) * DH + klane;
        ka[2 * mt]     = *(const short8*)(krow);
        ka[2 * mt + 1] = *(const short8*)(krow + 32);
    }

    #pragma unroll 1
    for (int iter = 0; iter < 16; ++iter, k0 += 64) {
        // ---- S^T = K @ Q^T from prefetched ka
        f32x4 c[2][4];
        #pragma unroll
        for (int mt = 0; mt < 4; ++mt)
            #pragma unroll
            for (int qs = 0; qs < 2; ++qs) {
                f32x4 z = (f32x4){0.f, 0.f, 0.f, 0.f};
                z = MFMA(ka[2 * mt],     bq[qs][0], z);
                z = MFMA(ka[2 * mt + 1], bq[qs][1], z);
                c[qs][mt] = z;
            }

        // ---- issue ALL V frag loads now; softmax below covers their latency
        short8 av[8];
        #pragma unroll
        for (int kch = 0; kch < 2; ++kch)
            #pragma unroll
            for (int dt = 0; dt < 4; ++dt)
                av[kch * 4 + dt] = *(const short8*)(vbase
                    + (size_t)(dt * 16) * SEQ + vlane + k0 + kch * 32);

        // ---- online softmax; c dies into packed W
        int W[2][8];
        #pragma unroll
        for (int qs = 0; qs < 2; ++qs) {
            float tm[4];
            #pragma unroll
            for (int e = 0; e < 4; ++e)
                tm[e] = fmaxf(fmaxf(c[qs][0][e], c[qs][1][e]),
                              fmaxf(c[qs][2][e], c[qs][3][e]));
            float vmax = fmaxf(fmaxf(tm[0], tm[1]), fmaxf(tm[2], tm[3]));
            vmax = fmaxf(vmax, m_i[qs]);
            vmax = fmaxf(vmax, __shfl_xor(vmax, 16, 64));
            vmax = fmaxf(vmax, __shfl_xor(vmax, 32, 64));
            const float alpha = __builtin_amdgcn_exp2f(m_i[qs] - vmax);
            m_i[qs] = vmax;

            float rs0 = 0.f, rs1 = 0.f;
            #pragma unroll
            for (int i2 = 0; i2 < 2; ++i2)
                #pragma unroll
                for (int r = 0; r < 4; ++r) {
                    float p0 = __builtin_amdgcn_exp2f(c[qs][2 * i2][r]     - vmax);
                    float p1 = __builtin_amdgcn_exp2f(c[qs][2 * i2 + 1][r] - vmax);
                    rs0 += p0; rs1 += p1;
                    W[qs][i2 * 4 + r] = (int)pack_bf162(p0, p1);
                }
            float rs = rs0 + rs1;
            rs += __shfl_xor(rs, 16, 64);
            rs += __shfl_xor(rs, 32, 64);
            l_i[qs] = l_i[qs] * alpha + rs;
            #pragma unroll
            for (int dt = 0; dt < 4; ++dt)
                #pragma unroll
                for (int r = 0; r < 4; ++r) o[qs][dt][r] *= alpha;
        }

        // ---- issue next iter's K loads (c dead; PV below covers latency)
        if (iter < 15) {
            #pragma unroll
            for (int mt = 0; mt < 4; ++mt) {
                const short* krow = kbase + (size_t)(k0 + 64 + mt * 16) * DH + klane;
                ka[2 * mt]     = *(const short8*)(krow);
                ka[2 * mt + 1] = *(const short8*)(krow + 32);
            }
        }

        // ---- transform + PV (av already resident)
        #pragma unroll
        for (int kch = 0; kch < 2; ++kch) {
            #pragma unroll
            for (int qs = 0; qs < 2; ++qs) {
                int sA[4], sB[4];
                #pragma unroll
                for (int r = 0; r < 4; ++r) {
                    int w = W[qs][kch * 4 + r];
                    sA[r] = __shfl(w, srcLo, 64);
                    sB[r] = __shfl(w, srcHi, 64);
                }
                int4v pw;
                pw[0] = (int)__builtin_amdgcn_perm((unsigned)sA[1], (unsigned)sA[0], psel);
                pw[1] = (int)__builtin_amdgcn_perm((unsigned)sA[3], (unsigned)sA[2], psel);
                pw[2] = (int)__builtin_amdgcn_perm((unsigned)sB[1], (unsigned)sB[0], psel);
                pw[3] = (int)__builtin_amdgcn_perm((unsigned)sB[3], (unsigned)sB[2], psel);
                short8 pf = __builtin_bit_cast(short8, pw);
                #pragma unroll
                for (int dt = 0; dt < 4; ++dt)
                    o[qs][dt] = MFMA(av[kch * 4 + dt], pf, o[qs][dt]);
            }
        }
    }

    // ---- cross-wave flash merge (khalf 1 -> LDS, khalf 0 combines+stores)
    if (khalf == 1) {
        #pragma unroll
        for (int qs = 0; qs < 2; ++qs) {
            #pragma unroll
            for (int dt = 0; dt < 4; ++dt)
                #pragma unroll
                for (int r = 0; r < 4; ++r)
                    lds_o[qgrp][qs][lane][dt * 4 + r] = o[qs][dt][r];
            if (quad == 0) {
                lds_m[qgrp][qs][l16] = m_i[qs];
                lds_l[qgrp][qs][l16] = l_i[qs];
            }
        }
    }
    __syncthreads();
    if (khalf == 0) {
        #pragma unroll
        for (int qs = 0; qs < 2; ++qs) {
            const float m2 = lds_m[qgrp][qs][l16];
            const float l2 = lds_l[qgrp][qs][l16];
            const float m  = fmaxf(m_i[qs], m2);
            const float a1 = __builtin_amdgcn_exp2f(m_i[qs] - m);
            const float a2 = __builtin_amdgcn_exp2f(m2 - m);
            const float linv = 1.0f / (l_i[qs] * a1 + l2 * a2);
            float* orow = og + ((size_t)(bh * SEQ + q0 + qs * 16 + l16)) * DH;
            #pragma unroll
            for (int dt = 0; dt < 4; ++dt) {
                f32x4 st;
                #pragma unroll
                for (int r = 0; r < 4; ++r)
                    st[r] = (o[qs][dt][r] * a1
                           + lds_o[qgrp][qs][lane][dt * 4 + r] * a2) * linv;
                *(f32x4*)(orow + dt * 16 + quad * 4) = st;
            }
        }
    }
}

extern "C" void kernel_launch(void* const* d_in, const int* in_sizes, int n_in,
                              void* d_out, int out_size, void* d_ws, size_t ws_size,
                              hipStream_t stream)
{
    const float* q = (const float*)d_in[0];
    const float* k = (const float*)d_in[1];
    const float* v = (const float*)d_in[2];
    float* o = (float*)d_out;

    const size_t nelem = (size_t)NBH * SEQ * DH;
    short* qb  = (short*)d_ws;
    short* kbp = qb + nelem;
    short* vtp = kbp + nelem;   // 18.9 MB total

    cvt_all<<<dim3(NBH, SEQ / 64, 2), 256, 0, stream>>>(q, k, v, qb, kbp, vtp);
    attn_fwd<<<dim3(NBH, SEQ / 64), 256, 0, stream>>>(qb, kbp, vtp, o);
}

// Round 11
// 175.399 us; speedup vs baseline: 1.3964x; 1.1194x over previous
//
#include <hip/hip_runtime.h>
#include <math.h>

#define SEQ   2048
#define DH    64
#define NBH   24
// scale * log2(e): softmax in exp2 domain
#define QSCALE 0.18033688011112042f

typedef __attribute__((ext_vector_type(8)))  short short8;
typedef __attribute__((ext_vector_type(4)))  float f32x4;
typedef __attribute__((ext_vector_type(16))) float f32x16;
typedef __attribute__((ext_vector_type(4)))  int   int4v;

#define MFMA32(a, b, c) __builtin_amdgcn_mfma_f32_32x32x16_bf16((a), (b), (c), 0, 0, 0)

__device__ __forceinline__ unsigned bf16u(float f) {   // RNE-rounded, result in high 16
    union { float f; unsigned u; } x; x.f = f;
    return x.u + 0x7fffu + ((x.u >> 16) & 1u);
}
__device__ __forceinline__ unsigned pack_bf162(float lo, float hi) {
    return (bf16u(lo) >> 16) | (bf16u(hi) & 0xffff0000u);
}

// ---- pre-pass: grid.z=0 -> Q(+scale),K fp32->bf16; grid.z=1 -> V -> V^T ----
__global__ __launch_bounds__(256)
void cvt_all(const float* __restrict__ q, const float* __restrict__ k,
             const float* __restrict__ v,
             short* __restrict__ qb, short* __restrict__ kb,
             short* __restrict__ vt)
{
    const int t  = threadIdx.x;
    const int bh = blockIdx.x;
    const int s0 = blockIdx.y * 64;
    const size_t base = ((size_t)bh * SEQ + s0) * DH;

    if (blockIdx.z == 0) {
        #pragma unroll
        for (int i = 0; i < 4; ++i) {
            const int idx = i * 256 + t;
            float4 a = ((const float4*)(q + base))[idx];
            ((int2*)(qb + base))[idx] = make_int2(
                (int)pack_bf162(a.x * QSCALE, a.y * QSCALE),
                (int)pack_bf162(a.z * QSCALE, a.w * QSCALE));
            float4 b = ((const float4*)(k + base))[idx];
            ((int2*)(kb + base))[idx] = make_int2(
                (int)pack_bf162(b.x, b.y), (int)pack_bf162(b.z, b.w));
        }
        return;
    }

    __shared__ float tile[64][65];
    {
        const int sl = t >> 2, cg = (t & 3) * 16;
        const float* src = v + base + (size_t)sl * DH + cg;
        #pragma unroll
        for (int i = 0; i < 4; ++i)
            *(float4*)(&tile[sl][cg + 4 * i]) = ((const float4*)src)[i];
    }
    __syncthreads();
    {
        const int dl = t >> 2, sg = (t & 3) * 16;
        float f[16];
        #pragma unroll
        for (int j = 0; j < 16; ++j) f[j] = tile[sg + j][dl];
        short8 r0, r1;
        #pragma unroll
        for (int j = 0; j < 4; ++j) {
            ((int*)&r0)[j] = (int)pack_bf162(f[2 * j],     f[2 * j + 1]);
            ((int*)&r1)[j] = (int)pack_bf162(f[8 + 2 * j], f[9 + 2 * j]);
        }
        short* dst = vt + (size_t)bh * DH * SEQ + (size_t)dl * SEQ + s0 + sg;
        *(short8*)(dst)     = r0;
        *(short8*)(dst + 8) = r1;
    }
}

// ---- main: split-K flash on 32x32 MFMA tiles ----
// Wave covers 32 q-rows as ONE N=32 MFMA tile: C/D col=lane&31=q-row,
// row=(reg&3)+8*(reg>>2)+4*(lane>>5) (HW-verified layout, m74/m101).
// vs R6 (16x16): MFMA instrs 32->16, reduction shfl 4->2, transform
// 32 bpermute+16 perm -> 8 shfl_xor+16 pack. Same VMEM count, same FLOPs,
// same ~148-reg live set. R6 issue order (compiler beat all manual reorders:
// R5/R9 spilled, R10 regressed). Tripwire: WRITE_SIZE ~12 MB, else spill.
__global__ __launch_bounds__(256, 3)
void attn_fwd(const short* __restrict__ qb, const short* __restrict__ kb,
              const short* __restrict__ vt, float* __restrict__ og)
{
    __shared__ float lds_o[2][64][32];
    __shared__ float lds_m[2][32];
    __shared__ float lds_l[2][32];

    const int lane  = threadIdx.x & 63;
    const int wave  = threadIdx.x >> 6;
    const int qgrp  = wave >> 1;
    const int khalf = wave & 1;
    const int half  = lane >> 5;          // K-dim half within MFMA frags
    const int l32   = lane & 31;          // q-row (B/C/D col) / A m-row
    const int bh    = blockIdx.x;
    const int q0    = blockIdx.y * 64 + qgrp * 32;

    const short* kbase = kb + (size_t)bh * SEQ * DH;
    const short* vbase = vt + (size_t)bh * DH * SEQ;

    // Q^T B-frags: B[k=d][n=q], lane holds q=l32, d = dg*16 + half*8 + j
    short8 bq[4];
    #pragma unroll
    for (int dg = 0; dg < 4; ++dg)
        bq[dg] = *(const short8*)(qb + ((size_t)(bh * SEQ + q0 + l32)) * DH
                                  + dg * 16 + half * 8);

    f32x16 o[2];
    #pragma unroll
    for (int dt = 0; dt < 2; ++dt)
        #pragma unroll
        for (int r = 0; r < 16; ++r) o[dt][r] = 0.f;
    float m_i = -INFINITY, l_i = 0.f;

    const size_t klane = (size_t)l32 * DH;
    const size_t vlane = (size_t)l32 * SEQ;

    // prologue: K A-frags of first 64-col chunk (2 mtiles x 4 d-groups)
    short8 ka[2][4];
    int k0 = khalf * (SEQ / 2);
    #pragma unroll
    for (int mt = 0; mt < 2; ++mt)
        #pragma unroll
        for (int dg = 0; dg < 4; ++dg)
            ka[mt][dg] = *(const short8*)(kbase + (size_t)(k0 + mt * 32) * DH
                                          + klane + dg * 16 + half * 8);

    #pragma unroll 1
    for (int iter = 0; iter < 16; ++iter, k0 += 64) {
        // ---- S^T = K @ Q^T : 2 M-tiles of 32 k-cols, K=16 x 4 steps
        f32x16 c[2];
        #pragma unroll
        for (int mt = 0; mt < 2; ++mt) {
            f32x16 z;
            #pragma unroll
            for (int r = 0; r < 16; ++r) z[r] = 0.f;
            #pragma unroll
            for (int dg = 0; dg < 4; ++dg)
                z = MFMA32(ka[mt][dg], bq[dg], z);
            c[mt] = z;
        }

        // ---- prefetch next chunk's K frags (covered by softmax+PV)
        if (iter < 15) {
            #pragma unroll
            for (int mt = 0; mt < 2; ++mt)
                #pragma unroll
                for (int dg = 0; dg < 4; ++dg)
                    ka[mt][dg] = *(const short8*)(kbase
                        + (size_t)(k0 + 64 + mt * 32) * DH
                        + klane + dg * 16 + half * 8);
        }

        // ---- online softmax: lane's 32 values all belong to q-row l32
        float t16[16];
        #pragma unroll
        for (int r = 0; r < 16; ++r) t16[r] = fmaxf(c[0][r], c[1][r]);
        #pragma unroll
        for (int r = 0; r < 8; ++r) t16[r] = fmaxf(t16[r], t16[r + 8]);
        #pragma unroll
        for (int r = 0; r < 4; ++r) t16[r] = fmaxf(t16[r], t16[r + 4]);
        float vmax = fmaxf(fmaxf(t16[0], t16[1]), fmaxf(t16[2], t16[3]));
        vmax = fmaxf(vmax, m_i);
        vmax = fmaxf(vmax, __shfl_xor(vmax, 32, 64));
        const float alpha = __builtin_amdgcn_exp2f(m_i - vmax);
        m_i = vmax;

        float rs0 = 0.f, rs1 = 0.f, rs2 = 0.f, rs3 = 0.f;
        #pragma unroll
        for (int mt = 0; mt < 2; ++mt)
            #pragma unroll
            for (int r = 0; r < 16; r += 4) {
                float p0 = __builtin_amdgcn_exp2f(c[mt][r]     - vmax);
                float p1 = __builtin_amdgcn_exp2f(c[mt][r + 1] - vmax);
                float p2 = __builtin_amdgcn_exp2f(c[mt][r + 2] - vmax);
                float p3 = __builtin_amdgcn_exp2f(c[mt][r + 3] - vmax);
                c[mt][r] = p0; c[mt][r + 1] = p1; c[mt][r + 2] = p2; c[mt][r + 3] = p3;
                rs0 += p0; rs1 += p1; rs2 += p2; rs3 += p3;
            }
        float rs = (rs0 + rs1) + (rs2 + rs3);
        rs += __shfl_xor(rs, 32, 64);
        l_i = l_i * alpha + rs;
        #pragma unroll
        for (int dt = 0; dt < 2; ++dt)
            #pragma unroll
            for (int r = 0; r < 16; ++r) o[dt][r] *= alpha;

        // ---- P^T -> B-frags (lane pairs only with lane^32), then PV
        // C rows r=(reg&3)+8*(reg>>2)+4*half; B-frag needs k=8*half+j per
        // 16-row k-group. Exchange: send own "other-quarter" pack, select.
        #pragma unroll
        for (int mt = 0; mt < 2; ++mt) {
            int w[8];
            #pragma unroll
            for (int g = 0; g < 8; ++g)
                w[g] = (int)pack_bf162(c[mt][2 * g], c[mt][2 * g + 1]);

            #pragma unroll
            for (int kg = 0; kg < 2; ++kg) {
                const int base = kg * 4;               // words: kg0 -> w0..3, kg1 -> w4..7
                // own quarters: pLo = (w[base],w[base+1]) rows q0..q3 of this half
                //               pHi = (w[base+2],w[base+3])
                int t0 = half ? w[base]     : w[base + 2];
                int t1 = half ? w[base + 1] : w[base + 3];
                int r0 = __shfl_xor(t0, 32, 64);
                int r1 = __shfl_xor(t1, 32, 64);
                int4v pw;
                pw[0] = half ? r0 : w[base];
                pw[1] = half ? r1 : w[base + 1];
                pw[2] = half ? w[base + 2] : r0;
                pw[3] = half ? w[base + 3] : r1;
                short8 pf = __builtin_bit_cast(short8, pw);

                #pragma unroll
                for (int dt = 0; dt < 2; ++dt) {
                    short8 av = *(const short8*)(vbase + (size_t)(dt * 32) * SEQ
                                + vlane + k0 + mt * 32 + kg * 16 + half * 8);
                    o[dt] = MFMA32(av, pf, o[dt]);
                }
            }
        }
    }

    // ---- cross-wave flash merge (khalf 1 -> LDS, khalf 0 combines+stores)
    if (khalf == 1) {
        #pragma unroll
        for (int dt = 0; dt < 2; ++dt)
            #pragma unroll
            for (int r = 0; r < 16; ++r)
                lds_o[qgrp][lane][dt * 16 + r] = o[dt][r];
        if (half == 0) { lds_m[qgrp][l32] = m_i; lds_l[qgrp][l32] = l_i; }
    }
    __syncthreads();
    if (khalf == 0) {
        const float m2 = lds_m[qgrp][l32];
        const float l2 = lds_l[qgrp][l32];
        const float m  = fmaxf(m_i, m2);
        const float a1 = __builtin_amdgcn_exp2f(m_i - m);
        const float a2 = __builtin_amdgcn_exp2f(m2 - m);
        const float linv = 1.0f / (l_i * a1 + l2 * a2);
        float* orow = og + ((size_t)(bh * SEQ + q0 + l32)) * DH;
        // o reg r of dtile dt -> d = dt*32 + 8*(r>>2) + 4*half + (r&3)
        #pragma unroll
        for (int dt = 0; dt < 2; ++dt)
            #pragma unroll
            for (int g = 0; g < 4; ++g) {
                f32x4 st;
                #pragma unroll
                for (int e = 0; e < 4; ++e)
                    st[e] = (o[dt][4 * g + e] * a1
                           + lds_o[qgrp][lane][dt * 16 + 4 * g + e] * a2) * linv;
                *(f32x4*)(orow + dt * 32 + 8 * g + 4 * half) = st;
            }
    }
}

extern "C" void kernel_launch(void* const* d_in, const int* in_sizes, int n_in,
                              void* d_out, int out_size, void* d_ws, size_t ws_size,
                              hipStream_t stream)
{
    const float* q = (const float*)d_in[0];
    const float* k = (const float*)d_in[1];
    const float* v = (const float*)d_in[2];
    float* o = (float*)d_out;

    const size_t nelem = (size_t)NBH * SEQ * DH;
    short* qb  = (short*)d_ws;
    short* kbp = qb + nelem;
    short* vtp = kbp + nelem;   // 18.9 MB total

    cvt_all<<<dim3(NBH, SEQ / 64, 2), 256, 0, stream>>>(q, k, v, qb, kbp, vtp);
    attn_fwd<<<dim3(NBH, SEQ / 64), 256, 0, stream>>>(qb, kbp, vtp, o);
}